// Round 5
// baseline (140.403 us; speedup 1.0000x reference)
//
#include <hip/hip_runtime.h>
#include <cmath>

#define BB 256
#define TT 16
#define SS 32
#define DD 768
#define LROW 260       // LDS staging row stride (floats), 16B-aligned
#define MAGIC 0x5AD0BEEFu

// ---------------------------------------------------------------------------
// Flag-based cross-block sync (agent scope). Poison-safe: flags live in the
// harness-re-poisoned workspace, so "!= MAGIC" == not ready this iteration.
// If an iteration ever runs without re-poison, flags are stale-MAGIC but the
// gated data is stale-identical (deterministic inputs) -> still correct.
// ---------------------------------------------------------------------------
__device__ __forceinline__ void flag_set(unsigned* p) {
    __hip_atomic_store(p, MAGIC, __ATOMIC_RELEASE, __HIP_MEMORY_SCOPE_AGENT);
}
__device__ __forceinline__ void flag_wait(unsigned* p) {
    while (__hip_atomic_load(p, __ATOMIC_ACQUIRE, __HIP_MEMORY_SCOPE_AGENT) != MAGIC)
        __builtin_amdgcn_s_sleep(2);
}

// ---------------------------------------------------------------------------
// wave-per-row LSE over cparts[p][3][256][256]; one atomicAdd per row.
// lane holds cols lane*4..+3 summed over the 8 K-partials. (verified R1-R3)
// ---------------------------------------------------------------------------
__device__ __forceinline__ void wave_lse(
    const float* __restrict__ cparts, float* __restrict__ out,
    int cm, int row, float w)
{
    const int lane = threadIdx.x & 63;
    float4 x = make_float4(0.f, 0.f, 0.f, 0.f);
    const float* base = cparts + (size_t)cm * 65536 + (size_t)row * 256 + (lane << 2);
#pragma unroll
    for (int p = 0; p < 8; ++p) {
        float4 v = *(const float4*)(base + (size_t)p * 3 * 65536);
        x.x += v.x; x.y += v.y; x.z += v.z; x.w += v.w;
    }
    float m = fmaxf(fmaxf(x.x, x.y), fmaxf(x.z, x.w));
#pragma unroll
    for (int off = 32; off > 0; off >>= 1)
        m = fmaxf(m, __shfl_xor(m, off, 64));
    float e = expf(x.x - m) + expf(x.y - m) + expf(x.z - m) + expf(x.w - m);
#pragma unroll
    for (int off = 32; off > 0; off >>= 1)
        e += __shfl_xor(e, off, 64);
    if (lane == (row >> 2)) {
        float lse = m + logf(e);
        float xd = (row & 2) ? ((row & 1) ? x.w : x.z)
                             : ((row & 1) ? x.y : x.x);
        atomicAdd(out, w * (lse - xd));
    }
}

// ---------------------------------------------------------------------------
// Fully fused kernel: 256 blocks x 512 threads (1 block/CU -> all blocks
// co-resident; flag sync is deadlock-free by capacity).
//   Phase A: stage1 for batch row i = blockIdx (R4-verified swizzled body);
//            block 0 also zeroes `out`. Release f1[i].
//   Phase B: gemm job = blockIdx (verified 256-thread body, act-guarded);
//            mat1 blocks first acquire the 128 producing f1 flags.
//            Release f2[job].
//   Phase C: wave-per-row LSE; global wave gw = blockIdx*8 + wave < 768.
//            Lanes 0..31 acquire the 32 producing f2 flags, lane 32 the
//            out-zero flag; then wave_lse.
// ---------------------------------------------------------------------------
__global__ __launch_bounds__(512) void hl_fused(
    const float* __restrict__ vg, const float* __restrict__ tg,
    const float* __restrict__ vl, const float* __restrict__ tl,
    const float* __restrict__ temp,
    float* __restrict__ vw_ws, float* __restrict__ tb_ws,
    float* __restrict__ cparts,
    unsigned* __restrict__ f1, unsigned* __restrict__ f2,
    unsigned* __restrict__ fo,
    float* __restrict__ out, int out_n)
{
    __shared__ float lds[13024];   // stage1: 12480 staging + 512 + 16 + 16
                                   // gemm:   As 1088 + Bs 1088 + Tb 4352

    const int tid = threadIdx.x;
    const float lsc = expf(temp[0]);

    // ====================== Phase A: stage1 =================================
    {
        float* smem = lds;            // [48][260]; aliased [512][17] transpose
        float* simb = lds + 12480;    // [512]
        float* rmax = lds + 12992;    // [16]
        float* twb  = lds + 13008;    // [16]
        const int i = blockIdx.x;

        if (i == 0) {                 // replaces hipMemsetAsync dispatch
            for (int o = tid; o < out_n; o += 512) out[o] = 0.f;
            __syncthreads();          // all zero-stores drained (vmcnt before barrier)
            if (tid == 0) flag_set(fo);
        }

        const int slice = tid & 15;   // d sub-offset: 16 lanes x 16B
        const int g     = tid >> 4;   // 0..31
        const int tg_   = g >> 3;     // 0..3  -> t rows tg_*4..+4
        const int sg    = g & 7;      // 0..7  -> s rows sg*4..+4

        const float* vli = vl + (size_t)i * TT * DD;
        const float* tli = tl + (size_t)i * SS * DD;

        float acc[4][4];
#pragma unroll
        for (int a = 0; a < 4; ++a)
#pragma unroll
            for (int b = 0; b < 4; ++b) acc[a][b] = 0.f;

        for (int c = 0; c < 3; ++c) {
            const int d0 = c << 8;
            // stage vl chunk 16x256, quad-swizzled LDS placement (R4-verified)
#pragma unroll
            for (int k = 0; k < 2; ++k) {
                int f4 = tid + (k << 9);
                int r  = f4 >> 6;
                int q  = f4 & 63;
                int pq = q ^ ((q >> 3) & 7);
                *(float4*)&smem[r * LROW + (pq << 2)] =
                    *(const float4*)&vli[r * DD + d0 + (q << 2)];
            }
            // stage tl chunk 32x256
#pragma unroll
            for (int k = 0; k < 4; ++k) {
                int f4 = tid + (k << 9);
                int r  = f4 >> 6;
                int q  = f4 & 63;
                int pq = q ^ ((q >> 3) & 7);
                *(float4*)&smem[(16 + r) * LROW + (pq << 2)] =
                    *(const float4*)&tli[r * DD + d0 + (q << 2)];
            }
            __syncthreads();
#pragma unroll
            for (int step = 0; step < 4; ++step) {
                const int db = (((slice << 2) + step) ^ (slice >> 1)) << 2;
                float4 av[4], bv[4];
#pragma unroll
                for (int ti = 0; ti < 4; ++ti)
                    av[ti] = *(const float4*)&smem[(tg_ * 4 + ti) * LROW + db];
#pragma unroll
                for (int sj = 0; sj < 4; ++sj)
                    bv[sj] = *(const float4*)&smem[(16 + sg * 4 + sj) * LROW + db];
#pragma unroll
                for (int ti = 0; ti < 4; ++ti)
#pragma unroll
                    for (int sj = 0; sj < 4; ++sj)
                        acc[ti][sj] += av[ti].x * bv[sj].x + av[ti].y * bv[sj].y
                                     + av[ti].z * bv[sj].z + av[ti].w * bv[sj].w;
            }
            __syncthreads();
        }

        // split-D transpose (alias staging region): [pair][slice], pad 17
#pragma unroll
        for (int ti = 0; ti < 4; ++ti)
#pragma unroll
            for (int sj = 0; sj < 4; ++sj) {
                int t = tg_ * 4 + ti, s = sg * 4 + sj;
                smem[(t * 32 + s) * 17 + slice] = acc[ti][sj];
            }
        __syncthreads();
        {   // pair `tid` reduce over 16 slices
            float ssum = 0.f;
#pragma unroll
            for (int k = 0; k < 16; ++k) ssum += smem[tid * 17 + k];
            simb[tid] = lsc * ssum;
        }
        __syncthreads();
        if (tid < 16) {               // rowmax over s (rotated)
            float m = -3.0e38f;
            for (int s = 0; s < 32; ++s)
                m = fmaxf(m, simb[tid * 32 + ((s + tid) & 31)]);
            rmax[tid] = m;
        }
        __syncthreads();
        if (tid == 0) {               // tw = softmax over 16 t values
            float M = -3.0e38f;
            for (int t = 0; t < 16; ++t) M = fmaxf(M, rmax[t]);
            float ssum = 0.f;
            for (int t = 0; t < 16; ++t) {
                float e = expf(rmax[t] - M);
                twb[t] = e;
                ssum += e;
            }
            float inv = 1.0f / ssum;
            for (int t = 0; t < 16; ++t) twb[t] *= inv;
        }
        __syncthreads();

        // vw / tb tails: coalesced, L2-hot re-read
        for (int d = tid; d < DD; d += 512) {
            float vwv = 0.f;
#pragma unroll
            for (int t = 0; t < 16; ++t) vwv += twb[t] * vli[t * DD + d];
            vw_ws[(size_t)i * DD + d] = vwv;
            float tbv = 0.f;
#pragma unroll
            for (int s = 0; s < 32; ++s) tbv += tli[s * DD + d];
            tb_ws[(size_t)i * DD + d] = tbv * (1.0f / 32.0f);
        }
        __syncthreads();              // all tail stores drained before release
        if (tid == 0) flag_set(f1 + i);
    }

    // ====================== Phase B: gemm ===================================
    {
        __syncthreads();              // LDS reuse guard (stage1 done with lds)
        float (*As)[68] = (float (*)[68])lds;
        float (*Bs)[68] = (float (*)[68])(lds + 1088);
        float (*Tb)[68] = (float (*)[68])(lds + 2176);

        const int b   = blockIdx.x;
        const int p   = b & 7;
        const int tj  = (b >> 3) & 3;
        const int ti  = (b >> 5) & 3;
        const int mat = b >> 7;
        const int i0 = ti * 64, j0 = tj * 64, kb0 = p * 96;

        if (mat == 1) {               // wait for the 128 producing stage1 rows
            if (tid < 128) {
                int row = (tid < 64) ? (i0 + tid) : (j0 + tid - 64);
                flag_wait(f1 + row);
            }
            __syncthreads();
        }

        const float* A  = mat ? vw_ws : vg;
        const float* Bm = mat ? tb_ws : tg;
        const bool act = tid < 256;
        const int srow = tid >> 2, skq = tid & 3;   // staging: row, k-quad
        const int tr = tid >> 4, tc = tid & 15;     // compute tile

        float acc[4][4];
#pragma unroll
        for (int r = 0; r < 4; ++r)
#pragma unroll
            for (int cc = 0; cc < 4; ++cc) acc[r][cc] = 0.f;

        for (int ch = 0; ch < 6; ++ch) {
            const int kb = kb0 + ch * 16;
            float4 a4, b4;
            if (act) {
                a4 = *(const float4*)&A [(size_t)(i0 + srow) * DD + kb + skq * 4];
                b4 = *(const float4*)&Bm[(size_t)(j0 + srow) * DD + kb + skq * 4];
            }
            __syncthreads();
            if (act) {
                As[skq * 4 + 0][srow] = a4.x; As[skq * 4 + 1][srow] = a4.y;
                As[skq * 4 + 2][srow] = a4.z; As[skq * 4 + 3][srow] = a4.w;
                Bs[skq * 4 + 0][srow] = b4.x; Bs[skq * 4 + 1][srow] = b4.y;
                Bs[skq * 4 + 2][srow] = b4.z; Bs[skq * 4 + 3][srow] = b4.w;
            }
            __syncthreads();
            if (act) {
#pragma unroll
                for (int k = 0; k < 16; ++k) {
                    float4 av = *(const float4*)&As[k][tr * 4];
                    float4 bv = *(const float4*)&Bs[k][tc * 4];
                    float ar[4] = {av.x, av.y, av.z, av.w};
                    float br[4] = {bv.x, bv.y, bv.z, bv.w};
#pragma unroll
                    for (int r = 0; r < 4; ++r)
#pragma unroll
                        for (int cc = 0; cc < 4; ++cc)
                            acc[r][cc] += ar[r] * br[cc];
                }
            }
        }

        const int cm = mat ? 0 : 1;
        float* Cp = cparts + ((size_t)p * 3 + cm) * 65536;
        if (act) {
#pragma unroll
            for (int r = 0; r < 4; ++r) {
                float4 v = {acc[r][0] * lsc, acc[r][1] * lsc,
                            acc[r][2] * lsc, acc[r][3] * lsc};
                *(float4*)&Cp[(size_t)(i0 + tr * 4 + r) * 256 + j0 + tc * 4] = v;
            }
        }
        if (mat == 0) {               // also write G^T for the t2v column-LSE
            __syncthreads();
            if (act) {
#pragma unroll
                for (int r = 0; r < 4; ++r)
#pragma unroll
                    for (int cc = 0; cc < 4; ++cc)
                        Tb[tc * 4 + cc][tr * 4 + r] = acc[r][cc] * lsc;
            }
            __syncthreads();
            if (act) {
                float* Ct = cparts + ((size_t)p * 3 + 2) * 65536;
#pragma unroll
                for (int r = 0; r < 4; ++r) {
                    float4 v = *(const float4*)&Tb[tr * 4 + r][tc * 4];
                    *(float4*)&Ct[(size_t)(j0 + tr * 4 + r) * 256 + i0 + tc * 4] = v;
                }
            }
        }
        __syncthreads();              // all cparts stores drained before release
        if (tid == 0) flag_set(f2 + b);
    }

    // ====================== Phase C: LSE ====================================
    {
        const int gw = (blockIdx.x << 3) + (tid >> 6);   // global wave id
        if (gw < 768) {
            const int cm   = gw >> 8;
            const int row  = gw & 255;
            const int lane = tid & 63;
            if (lane < 32) {          // acquire the 32 producing gemm jobs
                int job;
                if (cm == 0)      job = 128 + ((row >> 6) << 5) + lane;
                else if (cm == 1) job = ((row >> 6) << 5) + lane;
                else              job = ((lane >> 3) << 5) + ((row >> 6) << 3) + (lane & 7);
                flag_wait(f2 + job);
            }
            if (lane == 32) flag_wait(fo);   // out has been zeroed
            // wave reconverges here (lockstep); data loads follow acquires
            const float w = (cm == 0) ? (0.4f / 256.0f) : (0.3f / 256.0f);
            wave_lse(cparts, out, cm, row, w);
        }
    }
}

extern "C" void kernel_launch(void* const* d_in, const int* in_sizes, int n_in,
                              void* d_out, int out_size, void* d_ws, size_t ws_size,
                              hipStream_t stream)
{
    const float* vg   = (const float*)d_in[0];  // [256,768]
    const float* tg   = (const float*)d_in[1];  // [256,768]
    const float* vl   = (const float*)d_in[2];  // [256,16,768]
    const float* tl   = (const float*)d_in[3];  // [256,32,768]
    const float* temp = (const float*)d_in[4];  // [1]
    float* out = (float*)d_out;

    float* vw     = (float*)d_ws;                   // [256,768]
    float* tbw    = vw + (size_t)BB * DD;           // [256,768]
    float* cparts = tbw + (size_t)BB * DD;          // [8][3][256][256]
    unsigned* f1  = (unsigned*)(cparts + (size_t)8 * 3 * 65536);  // [256]
    unsigned* f2  = f1 + 256;                                     // [256]
    unsigned* fo  = f2 + 256;                                     // [1]

    hl_fused<<<dim3(BB), dim3(512), 0, stream>>>(vg, tg, vl, tl, temp,
                                                 vw, tbw, cparts,
                                                 f1, f2, fo, out, out_size);
}

// Round 6
// 118.017 us; speedup vs baseline: 1.1897x; 1.1897x over previous
//
#include <hip/hip_runtime.h>
#include <cmath>

#define BB 256
#define TT 16
#define SS 32
#define DD 768
#define LROW 260   // LDS staging row stride (floats), 16B-aligned

// ---------------------------------------------------------------------------
// hl_k1: 256 blocks x 512 threads (1 block/CU).
//   Phase A (all blocks): stage1 for batch row i = blockIdx — R4-verified
//     swizzled body. Block 0 also zeroes `out` (replaces memset dispatch).
//   Phase B (blocks 0..127): mat0 GEMM coda, G = ls*vg@tg^T -> cparts cm=1
//     (+ transpose into cm=2). mat0 depends ONLY on inputs, so same-block
//     sequential phasing needs no cross-block sync (R5 lesson: in-kernel
//     cross-XCD flag sync is a loss; dispatch boundaries are the cheap fence).
// ---------------------------------------------------------------------------
__global__ __launch_bounds__(512) void hl_k1(
    const float* __restrict__ vg, const float* __restrict__ tg,
    const float* __restrict__ vl, const float* __restrict__ tl,
    const float* __restrict__ temp,
    float* __restrict__ vw_ws, float* __restrict__ tb_ws,
    float* __restrict__ cparts, float* __restrict__ out, int out_n)
{
    __shared__ float lds[13024];   // A: staging 12480 + simb 512 + 16 + 16
                                   // B: As 1088 + Bs 1088 + Tb 4352 (aliased)
    const int tid = threadIdx.x;
    const float lsc = expf(temp[0]);

    // ====================== Phase A: stage1 (R4-verified) ===================
    {
        float* smem = lds;            // [48][260]; aliased [512][17] transpose
        float* simb = lds + 12480;    // [512]
        float* rmax = lds + 12992;    // [16]
        float* twb  = lds + 13008;    // [16]
        const int i = blockIdx.x;

        if (i == 0) {                 // replaces hipMemsetAsync dispatch;
            for (int o = tid; o < out_n; o += 512) out[o] = 0.f;
        }                             // ordered before lse by 2 dispatch bounds

        const int slice = tid & 15;   // d sub-offset: 16 lanes x 16B
        const int g     = tid >> 4;   // 0..31
        const int tg_   = g >> 3;     // 0..3  -> t rows tg_*4..+4
        const int sg    = g & 7;      // 0..7  -> s rows sg*4..+4

        const float* vli = vl + (size_t)i * TT * DD;
        const float* tli = tl + (size_t)i * SS * DD;

        float acc[4][4];
#pragma unroll
        for (int a = 0; a < 4; ++a)
#pragma unroll
            for (int b = 0; b < 4; ++b) acc[a][b] = 0.f;

        for (int c = 0; c < 3; ++c) {
            const int d0 = c << 8;
            // stage vl chunk 16x256, quad-swizzled LDS placement:
            // P(q) = q ^ ((q>>3)&7) spreads read quads over all bank groups
            // (av 4x and bv 4x serialization without it — R4: verified win)
#pragma unroll
            for (int k = 0; k < 2; ++k) {
                int f4 = tid + (k << 9);
                int r  = f4 >> 6;
                int q  = f4 & 63;
                int pq = q ^ ((q >> 3) & 7);
                *(float4*)&smem[r * LROW + (pq << 2)] =
                    *(const float4*)&vli[r * DD + d0 + (q << 2)];
            }
            // stage tl chunk 32x256
#pragma unroll
            for (int k = 0; k < 4; ++k) {
                int f4 = tid + (k << 9);
                int r  = f4 >> 6;
                int q  = f4 & 63;
                int pq = q ^ ((q >> 3) & 7);
                *(float4*)&smem[(16 + r) * LROW + (pq << 2)] =
                    *(const float4*)&tli[r * DD + d0 + (q << 2)];
            }
            __syncthreads();
#pragma unroll
            for (int step = 0; step < 4; ++step) {
                // logical quad q = 4*slice + step; (q>>3)&7 == slice>>1
                const int db = (((slice << 2) + step) ^ (slice >> 1)) << 2;
                float4 av[4], bv[4];
#pragma unroll
                for (int ti = 0; ti < 4; ++ti)
                    av[ti] = *(const float4*)&smem[(tg_ * 4 + ti) * LROW + db];
#pragma unroll
                for (int sj = 0; sj < 4; ++sj)
                    bv[sj] = *(const float4*)&smem[(16 + sg * 4 + sj) * LROW + db];
#pragma unroll
                for (int ti = 0; ti < 4; ++ti)
#pragma unroll
                    for (int sj = 0; sj < 4; ++sj)
                        acc[ti][sj] += av[ti].x * bv[sj].x + av[ti].y * bv[sj].y
                                     + av[ti].z * bv[sj].z + av[ti].w * bv[sj].w;
            }
            __syncthreads();
        }

        // split-D transpose (alias staging region): [pair][slice], pad 17
#pragma unroll
        for (int ti = 0; ti < 4; ++ti)
#pragma unroll
            for (int sj = 0; sj < 4; ++sj) {
                int t = tg_ * 4 + ti, s = sg * 4 + sj;
                smem[(t * 32 + s) * 17 + slice] = acc[ti][sj];
            }
        __syncthreads();
        {   // pair `tid` reduce over 16 slices
            float ssum = 0.f;
#pragma unroll
            for (int k = 0; k < 16; ++k) ssum += smem[tid * 17 + k];
            simb[tid] = lsc * ssum;
        }
        __syncthreads();
        if (tid < 16) {               // rowmax over s (rotated to avoid clash)
            float m = -3.0e38f;
            for (int s = 0; s < 32; ++s)
                m = fmaxf(m, simb[tid * 32 + ((s + tid) & 31)]);
            rmax[tid] = m;
        }
        __syncthreads();
        if (tid == 0) {               // tw = softmax over 16 t values
            float M = -3.0e38f;
            for (int t = 0; t < 16; ++t) M = fmaxf(M, rmax[t]);
            float ssum = 0.f;
            for (int t = 0; t < 16; ++t) {
                float e = expf(rmax[t] - M);
                twb[t] = e;
                ssum += e;
            }
            float inv = 1.0f / ssum;
            for (int t = 0; t < 16; ++t) twb[t] *= inv;
        }
        __syncthreads();

        // vw / tb tails: coalesced, L2-hot re-read
        for (int d = tid; d < DD; d += 512) {
            float vwv = 0.f;
#pragma unroll
            for (int t = 0; t < 16; ++t) vwv += twb[t] * vli[t * DD + d];
            vw_ws[(size_t)i * DD + d] = vwv;
            float tbv = 0.f;
#pragma unroll
            for (int s = 0; s < 32; ++s) tbv += tli[s * DD + d];
            tb_ws[(size_t)i * DD + d] = tbv * (1.0f / 32.0f);
        }
    }

    // ====================== Phase B: mat0 gemm coda =========================
    if (blockIdx.x < 128) {
        __syncthreads();              // all Phase-A LDS reads done before reuse
        float (*As)[68] = (float (*)[68])lds;
        float (*Bs)[68] = (float (*)[68])(lds + 1088);
        float (*Tb)[68] = (float (*)[68])(lds + 2176);

        const int b  = blockIdx.x;    // job 0..127 (mat 0)
        const int p  = b & 7;
        const int tj = (b >> 3) & 3;
        const int ti = (b >> 5) & 3;
        const int i0 = ti * 64, j0 = tj * 64, kb0 = p * 96;

        const bool act = tid < 256;
        const int srow = tid >> 2, skq = tid & 3;   // staging: row, k-quad
        const int tr = tid >> 4, tc = tid & 15;     // compute tile

        float acc[4][4];
#pragma unroll
        for (int r = 0; r < 4; ++r)
#pragma unroll
            for (int cc = 0; cc < 4; ++cc) acc[r][cc] = 0.f;

        for (int ch = 0; ch < 6; ++ch) {
            const int kb = kb0 + ch * 16;
            float4 a4, b4;
            if (act) {
                a4 = *(const float4*)&vg[(size_t)(i0 + srow) * DD + kb + skq * 4];
                b4 = *(const float4*)&tg[(size_t)(j0 + srow) * DD + kb + skq * 4];
            }
            __syncthreads();
            if (act) {
                As[skq * 4 + 0][srow] = a4.x; As[skq * 4 + 1][srow] = a4.y;
                As[skq * 4 + 2][srow] = a4.z; As[skq * 4 + 3][srow] = a4.w;
                Bs[skq * 4 + 0][srow] = b4.x; Bs[skq * 4 + 1][srow] = b4.y;
                Bs[skq * 4 + 2][srow] = b4.z; Bs[skq * 4 + 3][srow] = b4.w;
            }
            __syncthreads();
            if (act) {
#pragma unroll
                for (int k = 0; k < 16; ++k) {
                    float4 av = *(const float4*)&As[k][tr * 4];
                    float4 bv = *(const float4*)&Bs[k][tc * 4];
                    float ar[4] = {av.x, av.y, av.z, av.w};
                    float br[4] = {bv.x, bv.y, bv.z, bv.w};
#pragma unroll
                    for (int r = 0; r < 4; ++r)
#pragma unroll
                        for (int cc = 0; cc < 4; ++cc)
                            acc[r][cc] += ar[r] * br[cc];
                }
            }
        }

        if (act) {
            float* Cp = cparts + ((size_t)p * 3 + 1) * 65536;
#pragma unroll
            for (int r = 0; r < 4; ++r) {
                float4 v = {acc[r][0] * lsc, acc[r][1] * lsc,
                            acc[r][2] * lsc, acc[r][3] * lsc};
                *(float4*)&Cp[(size_t)(i0 + tr * 4 + r) * 256 + j0 + tc * 4] = v;
            }
        }
        __syncthreads();
        if (act) {                    // G^T for the t2v column-LSE
#pragma unroll
            for (int r = 0; r < 4; ++r)
#pragma unroll
                for (int cc = 0; cc < 4; ++cc)
                    Tb[tc * 4 + cc][tr * 4 + r] = acc[r][cc] * lsc;
        }
        __syncthreads();
        if (act) {
            float* Ct = cparts + ((size_t)p * 3 + 2) * 65536;
#pragma unroll
            for (int r = 0; r < 4; ++r) {
                float4 v = *(const float4*)&Tb[tr * 4 + r][tc * 4];
                *(float4*)&Ct[(size_t)(j0 + tr * 4 + r) * 256 + i0 + tc * 4] = v;
            }
        }
    }
}

// ---------------------------------------------------------------------------
// hl_gemm_m1: mat1 only — L = ls*vw@tb^T -> cparts cm=0.
// 128 blocks x 256 threads, body identical to R4's verified gemm (mat=1).
// The k1->k2 dispatch boundary is the cross-XCD fence for vw/tb.
// ---------------------------------------------------------------------------
__global__ __launch_bounds__(256) void hl_gemm_m1(
    const float* __restrict__ vw, const float* __restrict__ tb,
    const float* __restrict__ temp, float* __restrict__ cparts)
{
    __shared__ float As[16][68];
    __shared__ float Bs[16][68];

    const int b   = blockIdx.x;   // job 0..127
    const int p   = b & 7;
    const int tj  = (b >> 3) & 3;
    const int ti  = (b >> 5) & 3;
    const int tid = threadIdx.x;
    const float lsc = expf(temp[0]);

    const int i0 = ti * 64, j0 = tj * 64, kb0 = p * 96;
    const int srow = tid >> 2, skq = tid & 3;
    const int tr = tid >> 4, tc = tid & 15;

    float acc[4][4];
#pragma unroll
    for (int r = 0; r < 4; ++r)
#pragma unroll
        for (int cc = 0; cc < 4; ++cc) acc[r][cc] = 0.f;

    for (int ch = 0; ch < 6; ++ch) {
        const int kb = kb0 + ch * 16;
        float4 a4 = *(const float4*)&vw[(size_t)(i0 + srow) * DD + kb + skq * 4];
        float4 b4 = *(const float4*)&tb[(size_t)(j0 + srow) * DD + kb + skq * 4];
        __syncthreads();
        As[skq * 4 + 0][srow] = a4.x; As[skq * 4 + 1][srow] = a4.y;
        As[skq * 4 + 2][srow] = a4.z; As[skq * 4 + 3][srow] = a4.w;
        Bs[skq * 4 + 0][srow] = b4.x; Bs[skq * 4 + 1][srow] = b4.y;
        Bs[skq * 4 + 2][srow] = b4.z; Bs[skq * 4 + 3][srow] = b4.w;
        __syncthreads();
#pragma unroll
        for (int k = 0; k < 16; ++k) {
            float4 av = *(const float4*)&As[k][tr * 4];
            float4 bv = *(const float4*)&Bs[k][tc * 4];
            float ar[4] = {av.x, av.y, av.z, av.w};
            float br[4] = {bv.x, bv.y, bv.z, bv.w};
#pragma unroll
            for (int r = 0; r < 4; ++r)
#pragma unroll
                for (int cc = 0; cc < 4; ++cc)
                    acc[r][cc] += ar[r] * br[cc];
        }
    }

    float* Cp = cparts + (size_t)p * 3 * 65536;   // cm = 0
#pragma unroll
    for (int r = 0; r < 4; ++r) {
        float4 v = {acc[r][0] * lsc, acc[r][1] * lsc,
                    acc[r][2] * lsc, acc[r][3] * lsc};
        *(float4*)&Cp[(size_t)(i0 + tr * 4 + r) * 256 + j0 + tc * 4] = v;
    }
}

// ---------------------------------------------------------------------------
// hl_lse: 768 blocks = cm(3) x row(256). Sum 8 K-partials, block LSE,
// loss_row = lse - x[row]; weighted atomicAdd into out. (R4-verified)
//   cm 0: local rows (w=0.4/256), cm 1: G rows = v2t, cm 2: G^T rows = t2v
// ---------------------------------------------------------------------------
__global__ __launch_bounds__(256) void hl_lse(
    const float* __restrict__ cparts, float* __restrict__ out)
{
    __shared__ float xs[256];
    __shared__ float wred[4];
    __shared__ float bcast;

    const int b   = blockIdx.x;
    const int cm  = b >> 8;
    const int row = b & 255;
    const int tid = threadIdx.x;

    float x = 0.f;
#pragma unroll
    for (int p = 0; p < 8; ++p)
        x += cparts[((size_t)p * 3 + cm) * 65536 + (size_t)row * 256 + tid];
    xs[tid] = x;

    float m = x;
#pragma unroll
    for (int off = 32; off > 0; off >>= 1)
        m = fmaxf(m, __shfl_down(m, off, 64));
    if ((tid & 63) == 0) wred[tid >> 6] = m;
    __syncthreads();
    if (tid == 0)
        bcast = fmaxf(fmaxf(wred[0], wred[1]), fmaxf(wred[2], wred[3]));
    __syncthreads();
    float M = bcast;
    float e = expf(x - M);
#pragma unroll
    for (int off = 32; off > 0; off >>= 1)
        e += __shfl_down(e, off, 64);
    if ((tid & 63) == 0) wred[tid >> 6] = e;
    __syncthreads();
    if (tid == 0) {
        float Stot = wred[0] + wred[1] + wred[2] + wred[3];
        float lse  = M + logf(Stot);
        float w    = (cm == 0) ? (0.4f / 256.0f) : (0.3f / 256.0f);
        atomicAdd(out, w * (lse - xs[row]));
    }
}

extern "C" void kernel_launch(void* const* d_in, const int* in_sizes, int n_in,
                              void* d_out, int out_size, void* d_ws, size_t ws_size,
                              hipStream_t stream)
{
    const float* vg   = (const float*)d_in[0];  // [256,768]
    const float* tg   = (const float*)d_in[1];  // [256,768]
    const float* vl   = (const float*)d_in[2];  // [256,16,768]
    const float* tl   = (const float*)d_in[3];  // [256,32,768]
    const float* temp = (const float*)d_in[4];  // [1]
    float* out = (float*)d_out;

    float* vw     = (float*)d_ws;                   // [256,768]
    float* tbw    = vw + (size_t)BB * DD;           // [256,768]
    float* cparts = tbw + (size_t)BB * DD;          // [8][3][256][256]

    hl_k1     <<<dim3(BB),  dim3(512), 0, stream>>>(vg, tg, vl, tl, temp,
                                                    vw, tbw, cparts, out, out_size);
    hl_gemm_m1<<<dim3(128), dim3(256), 0, stream>>>(vw, tbw, temp, cparts);
    hl_lse    <<<dim3(768), dim3(256), 0, stream>>>(cparts, out);
}

// Round 7
// 112.102 us; speedup vs baseline: 1.2525x; 1.0528x over previous
//
#include <hip/hip_runtime.h>
#include <cmath>

#define BB 256
#define TT 16
#define SS 32
#define DD 768
#define LROW 260   // LDS staging row stride (floats), 16B-aligned

// ---------------------------------------------------------------------------
// stage1: per batch row i (256 blocks x 512 threads = 8 waves/CU)
//   sim[t][s] = ls*<vl[i,t,:], tl[i,s,:]>; tw = softmax_t(max_s sim)
//   vw[i,:] = sum_t tw[t]*vl[i,t,:];  tb[i,:] = mean_s tl[i,s,:]
// R4-verified body (LDS quad XOR-swizzle P(q)=q^((q>>3)&7): without it av
// reads hit 8/32 banks (4x serialization) and bv reads hit 8/32 banks (4x);
// P spreads quads over all bank groups -> HW-minimum aliasing).
// vs R4: block 0 also zeroes `out`, replacing the hipMemsetAsync dispatch
// (ordered before hl_lse's atomics by two dispatch boundaries).
// ---------------------------------------------------------------------------
__global__ __launch_bounds__(512) void hl_stage1(
    const float* __restrict__ vl, const float* __restrict__ tl,
    const float* __restrict__ temp,
    float* __restrict__ vw_ws, float* __restrict__ tb_ws,
    float* __restrict__ out, int out_n)
{
    __shared__ float smem[12480];   // 48 x 260 staging; aliased as 512x17 transpose
    __shared__ float simb[512];
    __shared__ float rmax[16];
    __shared__ float twb[16];

    const int i   = blockIdx.x;
    const int tid = threadIdx.x;
    const float lsc = expf(temp[0]);

    if (i == 0) {                 // replaces hipMemsetAsync dispatch
        for (int o = tid; o < out_n; o += 512) out[o] = 0.f;
    }

    const int slice = tid & 15;   // d sub-offset: 16 lanes x 16B
    const int g     = tid >> 4;   // 0..31
    const int tg    = g >> 3;     // 0..3  -> t rows tg*4..+4
    const int sg    = g & 7;      // 0..7  -> s rows sg*4..+4

    const float* vli = vl + (size_t)i * TT * DD;
    const float* tli = tl + (size_t)i * SS * DD;

    float acc[4][4];
#pragma unroll
    for (int a = 0; a < 4; ++a)
#pragma unroll
        for (int b = 0; b < 4; ++b) acc[a][b] = 0.f;

    for (int c = 0; c < 3; ++c) {
        const int d0 = c << 8;
        // stage vl chunk 16x256 (1024 float4, 2 per thread), coalesced global,
        // quad-swizzled LDS placement
#pragma unroll
        for (int k = 0; k < 2; ++k) {
            int f4 = tid + (k << 9);
            int r  = f4 >> 6;
            int q  = f4 & 63;                     // logical quad in row
            int pq = q ^ ((q >> 3) & 7);          // physical quad (swizzle)
            *(float4*)&smem[r * LROW + (pq << 2)] =
                *(const float4*)&vli[r * DD + d0 + (q << 2)];
        }
        // stage tl chunk 32x256 (2048 float4, 4 per thread)
#pragma unroll
        for (int k = 0; k < 4; ++k) {
            int f4 = tid + (k << 9);
            int r  = f4 >> 6;
            int q  = f4 & 63;
            int pq = q ^ ((q >> 3) & 7);
            *(float4*)&smem[(16 + r) * LROW + (pq << 2)] =
                *(const float4*)&tli[r * DD + d0 + (q << 2)];
        }
        __syncthreads();
#pragma unroll
        for (int step = 0; step < 4; ++step) {
            // logical quad q = 4*slice + step; (q>>3)&7 == slice>>1
            const int db = (((slice << 2) + step) ^ (slice >> 1)) << 2;
            float4 av[4], bv[4];
#pragma unroll
            for (int ti = 0; ti < 4; ++ti)
                av[ti] = *(const float4*)&smem[(tg * 4 + ti) * LROW + db];
#pragma unroll
            for (int sj = 0; sj < 4; ++sj)
                bv[sj] = *(const float4*)&smem[(16 + sg * 4 + sj) * LROW + db];
#pragma unroll
            for (int ti = 0; ti < 4; ++ti)
#pragma unroll
                for (int sj = 0; sj < 4; ++sj)
                    acc[ti][sj] += av[ti].x * bv[sj].x + av[ti].y * bv[sj].y
                                 + av[ti].z * bv[sj].z + av[ti].w * bv[sj].w;
        }
        __syncthreads();
    }

    // split-D transpose (alias staging region): [pair][slice], pad 17
#pragma unroll
    for (int ti = 0; ti < 4; ++ti)
#pragma unroll
        for (int sj = 0; sj < 4; ++sj) {
            int t = tg * 4 + ti, s = sg * 4 + sj;
            smem[(t * 32 + s) * 17 + slice] = acc[ti][sj];
        }
    __syncthreads();
    {   // pair `tid` reduce over 16 slices
        float ssum = 0.f;
#pragma unroll
        for (int k = 0; k < 16; ++k) ssum += smem[tid * 17 + k];
        simb[tid] = lsc * ssum;
    }
    __syncthreads();
    if (tid < 16) {               // rowmax over s (rotated to avoid bank clash)
        float m = -3.0e38f;
        for (int s = 0; s < 32; ++s)
            m = fmaxf(m, simb[tid * 32 + ((s + tid) & 31)]);
        rmax[tid] = m;
    }
    __syncthreads();
    if (tid == 0) {               // tw = softmax over 16 t values
        float M = -3.0e38f;
        for (int t = 0; t < 16; ++t) M = fmaxf(M, rmax[t]);
        float ssum = 0.f;
        for (int t = 0; t < 16; ++t) {
            float e = expf(rmax[t] - M);
            twb[t] = e;
            ssum += e;
        }
        float inv = 1.0f / ssum;
        for (int t = 0; t < 16; ++t) twb[t] *= inv;
    }
    __syncthreads();

    // vw / tb tails: coalesced, L2-hot re-read
    for (int d = tid; d < DD; d += 512) {
        float vwv = 0.f;
#pragma unroll
        for (int t = 0; t < 16; ++t) vwv += twb[t] * vli[t * DD + d];
        vw_ws[(size_t)i * DD + d] = vwv;
        float tbv = 0.f;
#pragma unroll
        for (int s = 0; s < 32; ++s) tbv += tli[s * DD + d];
        tb_ws[(size_t)i * DD + d] = tbv * (1.0f / 32.0f);
    }
}

// ---------------------------------------------------------------------------
// hl_gemm: 256 blocks = mat(2) x ti(4) x tj(4) x p(8 K-splits of 96)
//   mat 0: G = ls*vg@tg^T  -> cparts[p][1] and transposed into cparts[p][2]
//   mat 1: L = ls*vw@tb^T  -> cparts[p][0]
// 64x64 tile, LDS-staged (As/Bs k-major), 4x4 register tile per thread.
// (R4-verified; As reads broadcast, Bs reads 2 words/bank = HW minimum.)
// ---------------------------------------------------------------------------
__global__ __launch_bounds__(256) void hl_gemm(
    const float* __restrict__ vg, const float* __restrict__ tg,
    const float* __restrict__ vw, const float* __restrict__ tb,
    const float* __restrict__ temp, float* __restrict__ cparts)
{
    __shared__ float As[16][68];
    __shared__ float Bs[16][68];
    __shared__ float Tb[64][68];

    const int b   = blockIdx.x;
    const int p   = b & 7;
    const int tj  = (b >> 3) & 3;
    const int ti  = (b >> 5) & 3;
    const int mat = b >> 7;
    const int tid = threadIdx.x;
    const float lsc = expf(temp[0]);

    const float* A  = mat ? vw : vg;
    const float* Bm = mat ? tb : tg;
    const int i0 = ti * 64, j0 = tj * 64, kb0 = p * 96;

    const int srow = tid >> 2, skq = tid & 3;   // staging: row, k-quad
    const int tr = tid >> 4, tc = tid & 15;     // compute: 4 rows, 4 cols each

    float acc[4][4];
#pragma unroll
    for (int r = 0; r < 4; ++r)
#pragma unroll
        for (int cc = 0; cc < 4; ++cc) acc[r][cc] = 0.f;

    for (int ch = 0; ch < 6; ++ch) {
        const int kb = kb0 + ch * 16;
        float4 a4 = *(const float4*)&A [(size_t)(i0 + srow) * DD + kb + skq * 4];
        float4 b4 = *(const float4*)&Bm[(size_t)(j0 + srow) * DD + kb + skq * 4];
        __syncthreads();
        As[skq * 4 + 0][srow] = a4.x; As[skq * 4 + 1][srow] = a4.y;
        As[skq * 4 + 2][srow] = a4.z; As[skq * 4 + 3][srow] = a4.w;
        Bs[skq * 4 + 0][srow] = b4.x; Bs[skq * 4 + 1][srow] = b4.y;
        Bs[skq * 4 + 2][srow] = b4.z; Bs[skq * 4 + 3][srow] = b4.w;
        __syncthreads();
#pragma unroll
        for (int k = 0; k < 16; ++k) {
            float4 av = *(const float4*)&As[k][tr * 4];
            float4 bv = *(const float4*)&Bs[k][tc * 4];
            float ar[4] = {av.x, av.y, av.z, av.w};
            float br[4] = {bv.x, bv.y, bv.z, bv.w};
#pragma unroll
            for (int r = 0; r < 4; ++r)
#pragma unroll
                for (int cc = 0; cc < 4; ++cc)
                    acc[r][cc] += ar[r] * br[cc];
        }
    }

    const int cm = mat ? 0 : 1;
    float* Cp = cparts + ((size_t)p * 3 + cm) * 65536;
#pragma unroll
    for (int r = 0; r < 4; ++r) {
        float4 v = {acc[r][0] * lsc, acc[r][1] * lsc, acc[r][2] * lsc, acc[r][3] * lsc};
        *(float4*)&Cp[(size_t)(i0 + tr * 4 + r) * 256 + j0 + tc * 4] = v;
    }
    if (mat == 0) {   // also write G^T for the t2v column-LSE
        __syncthreads();
#pragma unroll
        for (int r = 0; r < 4; ++r)
#pragma unroll
            for (int cc = 0; cc < 4; ++cc)
                Tb[tc * 4 + cc][tr * 4 + r] = acc[r][cc] * lsc;
        __syncthreads();
        float* Ct = cparts + ((size_t)p * 3 + 2) * 65536;
#pragma unroll
        for (int r = 0; r < 4; ++r) {
            float4 v = *(const float4*)&Tb[tr * 4 + r][tc * 4];
            *(float4*)&Ct[(size_t)(j0 + tr * 4 + r) * 256 + i0 + tc * 4] = v;
        }
    }
}

// ---------------------------------------------------------------------------
// hl_lse: 768 blocks = cm(3) x row(256). Sum 8 K-partials, block LSE,
// loss_row = lse - x[row]; weighted atomicAdd into out. (R4-verified)
//   cm 0: local rows (w=0.4/256), cm 1: G rows = v2t, cm 2: G^T rows = t2v
// ---------------------------------------------------------------------------
__global__ __launch_bounds__(256) void hl_lse(
    const float* __restrict__ cparts, float* __restrict__ out)
{
    __shared__ float xs[256];
    __shared__ float wred[4];
    __shared__ float bcast;

    const int b   = blockIdx.x;
    const int cm  = b >> 8;
    const int row = b & 255;
    const int tid = threadIdx.x;

    float x = 0.f;
#pragma unroll
    for (int p = 0; p < 8; ++p)
        x += cparts[((size_t)p * 3 + cm) * 65536 + (size_t)row * 256 + tid];
    xs[tid] = x;

    float m = x;
#pragma unroll
    for (int off = 32; off > 0; off >>= 1)
        m = fmaxf(m, __shfl_down(m, off, 64));
    if ((tid & 63) == 0) wred[tid >> 6] = m;
    __syncthreads();
    if (tid == 0)
        bcast = fmaxf(fmaxf(wred[0], wred[1]), fmaxf(wred[2], wred[3]));
    __syncthreads();
    float M = bcast;
    float e = expf(x - M);
#pragma unroll
    for (int off = 32; off > 0; off >>= 1)
        e += __shfl_down(e, off, 64);
    if ((tid & 63) == 0) wred[tid >> 6] = e;
    __syncthreads();
    if (tid == 0) {
        float Stot = wred[0] + wred[1] + wred[2] + wred[3];
        float lse  = M + logf(Stot);
        float w    = (cm == 0) ? (0.4f / 256.0f) : (0.3f / 256.0f);
        atomicAdd(out, w * (lse - xs[row]));
    }
}

extern "C" void kernel_launch(void* const* d_in, const int* in_sizes, int n_in,
                              void* d_out, int out_size, void* d_ws, size_t ws_size,
                              hipStream_t stream)
{
    const float* vg   = (const float*)d_in[0];  // [256,768]
    const float* tg   = (const float*)d_in[1];  // [256,768]
    const float* vl   = (const float*)d_in[2];  // [256,16,768]
    const float* tl   = (const float*)d_in[3];  // [256,32,768]
    const float* temp = (const float*)d_in[4];  // [1]
    float* out = (float*)d_out;

    float* vw     = (float*)d_ws;                   // [256,768]
    float* tb     = vw + (size_t)BB * DD;           // [256,768]
    float* cparts = tb + (size_t)BB * DD;           // [8][3][256][256]

    hl_stage1<<<dim3(BB),  dim3(512), 0, stream>>>(vl, tl, temp, vw, tb,
                                                   out, out_size);
    hl_gemm  <<<dim3(256), dim3(256), 0, stream>>>(vg, tg, vw, tb, temp, cparts);
    hl_lse   <<<dim3(768), dim3(256), 0, stream>>>(cparts, out);
}